// Round 5
// baseline (116.280 us; speedup 1.0000x reference)
//
#include <hip/hip_runtime.h>
#include <cstdint>

#define NN 4096
#define DD 128
#define NB 16
#define JSPLIT 4
#define JRANGE (NN / JSPLIT)   // 1024 j per block (4 waves x 256 j)
#define WJ (JRANGE / 4)        // 256 j per wave
#define NCH (WJ / 16)          // 16 chunks of 16 j per wave

typedef __attribute__((ext_vector_type(8))) short short8;
typedef __attribute__((ext_vector_type(4))) float f32x4;
typedef unsigned short u16;

// fold scale (1/sqrt(D)) and log2(e) into everything once:
#define S2 (0.088388347648318447f * 1.4426950408889634f)

__device__ __forceinline__ u16 f2bf(float f) {
  union { float f; unsigned int u; } v; v.f = f;
  unsigned int u = v.u;
  u += 0x7fffu + ((u >> 16) & 1u);   // round-to-nearest-even
  return (u16)(u >> 16);
}

// ---------------------------------------------------------------------------
// Kernel 1: per-row precompute (unchanged from round 3 — verified).
//   Qbh[r][d] = bf16( (q_b[d]+pe[r][d]) * S2 )
//   Kbh[r][d] = bf16(  k_b[d]+pe[r][d] )
//   A2[r] = S2 * q_w·(k_b+pe_r),  B2[r] = S2 * k_w·(q_b+pe_r),  c2 = S2 * q_w·k_w
// ---------------------------------------------------------------------------
__global__ void precomp_kernel(const float* __restrict__ q_w, const float* __restrict__ q_b,
                               const float* __restrict__ k_w, const float* __restrict__ k_b,
                               const float* __restrict__ pe,
                               u16* __restrict__ Qbh, u16* __restrict__ Kbh,
                               float* __restrict__ A2, float* __restrict__ B2,
                               float* __restrict__ c2p) {
  const int t = threadIdx.x, lane = t & 63, wv = t >> 6;
  const int row = blockIdx.x * 4 + wv;

  const float p0 = pe[row * DD + lane];
  const float p1 = pe[row * DD + 64 + lane];
  const float qv0 = q_b[lane] + p0, qv1 = q_b[lane + 64] + p1;
  const float kv0 = k_b[lane] + p0, kv1 = k_b[lane + 64] + p1;
  const float qw0 = q_w[lane], qw1 = q_w[lane + 64];
  const float kw0 = k_w[lane], kw1 = k_w[lane + 64];

  Qbh[row * DD + lane]      = f2bf(qv0 * S2);
  Qbh[row * DD + 64 + lane] = f2bf(qv1 * S2);
  Kbh[row * DD + lane]      = f2bf(kv0);
  Kbh[row * DD + 64 + lane] = f2bf(kv1);

  float asum = qw0 * kv0 + qw1 * kv1;
  float bsum = kw0 * qv0 + kw1 * qv1;
#pragma unroll
  for (int m = 1; m < 64; m <<= 1) {
    asum += __shfl_xor(asum, m);
    bsum += __shfl_xor(bsum, m);
  }
  if (lane == 0) { A2[row] = S2 * asum; B2[row] = S2 * bsum; }

  if (row == 0) {
    float csum = qw0 * kw0 + qw1 * kw1;
#pragma unroll
    for (int m = 1; m < 64; m <<= 1) csum += __shfl_xor(csum, m);
    if (lane == 0) *c2p = S2 * csum;
  }
}

// ---------------------------------------------------------------------------
// Kernel 2: main. Grid (NN/16, JSPLIT), 256 threads (4 independent waves).
// Wave w owns i-rows [i0, i0+16) x j in [js*JRANGE + w*WJ, +WJ) x all 16 b.
// Swapped-operand MFMA: acc = mfma(A=Kb_j rows, B=Qb_i rows) puts
//   i = lane&15 (fixed per lane), j = j0c + 4*(lane>>4) + v  IN REGISTERS —
// no LDS in the hot path at all.  Score:
//   s = xj*V_b + (xi*A2_j + M_ij),  V_b = c2*xi + B2_i   (2 fma/element)
//   p = exp2(s);  l_b += p;  o_b += p*xj
// LDS (8 KB) used only for the end-of-kernel cross-wave reduction.
// ---------------------------------------------------------------------------
__global__ void attn_main(
    const float* __restrict__ x, const u16* __restrict__ Qbh,
    const u16* __restrict__ Kbh, const float* __restrict__ A2,
    const float* __restrict__ B2, const float* __restrict__ c2p,
    float* __restrict__ part_l, float* __restrict__ part_o) {
  __shared__ float red[2048];   // [l/o][w][b][i]

  const int t = threadIdx.x;
  const int lane = t & 63, w = t >> 6;
  const int il = lane & 15, h = lane >> 4;
  const int i0 = blockIdx.x * 16;
  const int js = blockIdx.y;
  const int jwave = js * JRANGE + w * WJ;

  const float c2 = *c2p;
  const float B2i = B2[i0 + il];

  // Q fragments for this i-tile (B-operand), loaded once.
  short8 qfr[4];
#pragma unroll
  for (int ks = 0; ks < 4; ++ks)
    qfr[ks] = *(const short8*)(Qbh + (i0 + il) * DD + ks * 32 + h * 8);

  // x[b][i] for all 16 batches (this lane's i).
  float xi[16];
#pragma unroll
  for (int b = 0; b < 16; ++b) xi[b] = x[b * NN + i0 + il];

  float l[16], o[16];
#pragma unroll
  for (int b = 0; b < 16; ++b) { l[b] = 0.f; o[b] = 0.f; }

  const float* xjb = x + jwave + 4 * h;               // + b*NN + c*16
  const float* a2b = A2 + jwave + 4 * h;              // + c*16
  const u16*   kb  = Kbh + (jwave + il) * DD + h * 8; // + c*16*DD + ks*32

  // prologue: K-frags + A2 for chunk 0, x ring depth 4
  short8 kfr[4];
#pragma unroll
  for (int ks = 0; ks < 4; ++ks) kfr[ks] = *(const short8*)(kb + ks * 32);
  float4 a2c = *(const float4*)(a2b);
  float4 a2n = a2c;
  float4 xq[4];
#pragma unroll
  for (int b = 0; b < 4; ++b) xq[b] = *(const float4*)(xjb + b * NN);

  for (int c = 0; c < NCH; ++c) {
    // M' tile for this chunk: lane holds i = il, j = j0c + 4h + v
    f32x4 acc = {0.f, 0.f, 0.f, 0.f};
#pragma unroll
    for (int ks = 0; ks < 4; ++ks)
      acc = __builtin_amdgcn_mfma_f32_16x16x32_bf16(kfr[ks], qfr[ks], acc, 0, 0, 0);

    // prefetch next chunk's K-frags + A2 (lands during ~800-cycle hot loop)
    if (c + 1 < NCH) {
      const u16* kbn = kb + (c + 1) * 16 * DD;
#pragma unroll
      for (int ks = 0; ks < 4; ++ks) kfr[ks] = *(const short8*)(kbn + ks * 32);
      a2n = *(const float4*)(a2b + (c + 1) * 16);
    }

#pragma unroll
    for (int b = 0; b < 16; ++b) {
      const float4 xv = xq[b & 3];
      // refill ring slot 4 iterations ahead (crosses into next chunk)
      if (b + 4 < 16) {
        xq[b & 3] = *(const float4*)(xjb + (b + 4) * NN + c * 16);
      } else if (c + 1 < NCH) {
        xq[b & 3] = *(const float4*)(xjb + (b + 4 - 16) * NN + (c + 1) * 16);
      }

      const float Vb = fmaf(c2, xi[b], B2i);
      const float t0 = fmaf(xi[b], a2c.x, acc[0]);
      const float t1 = fmaf(xi[b], a2c.y, acc[1]);
      const float t2 = fmaf(xi[b], a2c.z, acc[2]);
      const float t3 = fmaf(xi[b], a2c.w, acc[3]);
      const float s0 = fmaf(xv.x, Vb, t0);
      const float s1 = fmaf(xv.y, Vb, t1);
      const float s2 = fmaf(xv.z, Vb, t2);
      const float s3 = fmaf(xv.w, Vb, t3);
      const float e0 = __builtin_amdgcn_exp2f(s0);
      const float e1 = __builtin_amdgcn_exp2f(s1);
      const float e2 = __builtin_amdgcn_exp2f(s2);
      const float e3 = __builtin_amdgcn_exp2f(s3);
      l[b] += (e0 + e1) + (e2 + e3);
      float ob = o[b];
      ob = fmaf(e0, xv.x, ob);
      ob = fmaf(e1, xv.y, ob);
      ob = fmaf(e2, xv.z, ob);
      ob = fmaf(e3, xv.w, ob);
      o[b] = ob;
    }
    a2c = a2n;
  }

  // reduce over h (lanes il, il+16, il+32, il+48 hold disjoint j subsets)
#pragma unroll
  for (int b = 0; b < 16; ++b) {
    float lv = l[b], ov = o[b];
    lv += __shfl_xor(lv, 16); lv += __shfl_xor(lv, 32);
    ov += __shfl_xor(ov, 16); ov += __shfl_xor(ov, 32);
    if (h == 0) {
      red[(w * 16 + b) * 16 + il]        = lv;
      red[1024 + (w * 16 + b) * 16 + il] = ov;
    }
  }
  __syncthreads();

  // cross-wave combine: thread t -> (b = t>>4, i = t&15)
  {
    const int b = t >> 4, ii = t & 15;
    float lsum = 0.f, osum = 0.f;
#pragma unroll
    for (int ww = 0; ww < 4; ++ww) {
      lsum += red[(ww * 16 + b) * 16 + ii + 0];
      osum += red[1024 + (ww * 16 + b) * 16 + ii];
    }
    const int outidx = (js * NB + b) * NN + i0 + ii;
    part_l[outidx] = lsum;
    part_o[outidx] = osum;
  }
}

// ---------------------------------------------------------------------------
// Kernel 3: deterministic combine of the JSPLIT partial sums; out = Σo / Σl.
// ---------------------------------------------------------------------------
__global__ void combine_kernel(const float* __restrict__ part_l,
                               const float* __restrict__ part_o,
                               float* __restrict__ out) {
  const int id = blockIdx.x * 256 + threadIdx.x;  // b*NN + i
  float l = 0.f, o = 0.f;
#pragma unroll
  for (int js = 0; js < JSPLIT; ++js) {
    l += part_l[js * (NB * NN) + id];
    o += part_o[js * (NB * NN) + id];
  }
  out[id] = o / l;
}

extern "C" void kernel_launch(void* const* d_in, const int* in_sizes, int n_in,
                              void* d_out, int out_size, void* d_ws, size_t ws_size,
                              hipStream_t stream) {
  const float* x   = (const float*)d_in[0];
  const float* q_w = (const float*)d_in[1];
  const float* q_b = (const float*)d_in[2];
  const float* k_w = (const float*)d_in[3];
  const float* k_b = (const float*)d_in[4];
  const float* pe  = (const float*)d_in[5];
  float* out = (float*)d_out;

  // workspace layout (~4.05 MB total, same as round 3)
  char* ws = (char*)d_ws;
  u16*   Qbh    = (u16*)(ws);                                    // 1 MB
  u16*   Kbh    = (u16*)(ws + (1u << 20));                       // 1 MB
  float* A2     = (float*)(ws + (2u << 20));                     // 16 KB
  float* B2     = (float*)(ws + (2u << 20) + (16u << 10));       // 16 KB
  float* c2p    = (float*)(ws + (2u << 20) + (32u << 10));       // 64 B
  float* part_l = (float*)(ws + (2u << 20) + (48u << 10));       // 1 MB
  float* part_o = (float*)(ws + (2u << 20) + (48u << 10) + (1u << 20)); // 1 MB

  precomp_kernel<<<NN / 4, 256, 0, stream>>>(q_w, q_b, k_w, k_b, pe,
                                             Qbh, Kbh, A2, B2, c2p);
  attn_main<<<dim3(NN / 16, JSPLIT), 256, 0, stream>>>(x, Qbh, Kbh, A2, B2, c2p,
                                                       part_l, part_o);
  combine_kernel<<<(NB * NN) / 256, 256, 0, stream>>>(part_l, part_o, out);
}

// Round 6
// 67.675 us; speedup vs baseline: 1.7182x; 1.7182x over previous
//
#include <hip/hip_runtime.h>
#include <cstdint>

#define NN 4096
#define DD 128
#define NB 16
#define JSPLIT 8
#define JRANGE (NN / JSPLIT)   // 512 j per block
#define WJ (JRANGE / 4)        // 128 j per wave
#define NCH (WJ / 16)          // 8 chunks of 16 j per wave

typedef __attribute__((ext_vector_type(8))) short short8;
typedef __attribute__((ext_vector_type(4))) float f32x4;
typedef unsigned short u16;

// fold scale (1/sqrt(D)) and log2(e) into everything once:
#define S2 (0.088388347648318447f * 1.4426950408889634f)

__device__ __forceinline__ u16 f2bf(float f) {
  union { float f; unsigned int u; } v; v.f = f;
  unsigned int u = v.u;
  u += 0x7fffu + ((u >> 16) & 1u);   // round-to-nearest-even
  return (u16)(u >> 16);
}

// ---------------------------------------------------------------------------
// Kernel 1: per-row precompute (unchanged — verified rounds 3/4).
//   Qbh[r][d] = bf16( (q_b[d]+pe[r][d]) * S2 )
//   Kbh[r][d] = bf16(  k_b[d]+pe[r][d] )
//   A2[r] = S2 * q_w·(k_b+pe_r),  B2[r] = S2 * k_w·(q_b+pe_r),  c2 = S2 * q_w·k_w
// ---------------------------------------------------------------------------
__global__ void precomp_kernel(const float* __restrict__ q_w, const float* __restrict__ q_b,
                               const float* __restrict__ k_w, const float* __restrict__ k_b,
                               const float* __restrict__ pe,
                               u16* __restrict__ Qbh, u16* __restrict__ Kbh,
                               float* __restrict__ A2, float* __restrict__ B2,
                               float* __restrict__ c2p) {
  const int t = threadIdx.x, lane = t & 63, wv = t >> 6;
  const int row = blockIdx.x * 4 + wv;

  const float p0 = pe[row * DD + lane];
  const float p1 = pe[row * DD + 64 + lane];
  const float qv0 = q_b[lane] + p0, qv1 = q_b[lane + 64] + p1;
  const float kv0 = k_b[lane] + p0, kv1 = k_b[lane + 64] + p1;
  const float qw0 = q_w[lane], qw1 = q_w[lane + 64];
  const float kw0 = k_w[lane], kw1 = k_w[lane + 64];

  Qbh[row * DD + lane]      = f2bf(qv0 * S2);
  Qbh[row * DD + 64 + lane] = f2bf(qv1 * S2);
  Kbh[row * DD + lane]      = f2bf(kv0);
  Kbh[row * DD + 64 + lane] = f2bf(kv1);

  float asum = qw0 * kv0 + qw1 * kv1;
  float bsum = kw0 * qv0 + kw1 * qv1;
#pragma unroll
  for (int m = 1; m < 64; m <<= 1) {
    asum += __shfl_xor(asum, m);
    bsum += __shfl_xor(bsum, m);
  }
  if (lane == 0) { A2[row] = S2 * asum; B2[row] = S2 * bsum; }

  if (row == 0) {
    float csum = qw0 * kw0 + qw1 * kw1;
#pragma unroll
    for (int m = 1; m < 64; m <<= 1) csum += __shfl_xor(csum, m);
    if (lane == 0) *c2p = S2 * csum;
  }
}

// ---------------------------------------------------------------------------
// Kernel 2: main. Grid (NN/16, JSPLIT), 256 threads (4 waves).
// Block owns 16 i-rows x 512-j slice x all 16 b; wave w takes j sub-slice
// [w*128, w*128+128).  x-slice (16b x 512j, 32 KB) and A2-slice (2 KB) are
// staged in LDS ONCE per block — the hot loop has ZERO global loads except
// the 4 K-fragment loads per 16-j chunk (covered by ~700 cyc of compute).
// Swapped-operand MFMA keeps M' in registers: i = lane&15, j = 4*(lane>>4)+v.
//   s = xj*Vb + (xi*A2_j + M_ij),  Vb = c2*xi + B2_i
//   p = exp2(s);  l_b += p;  o_b += p*xj
// x reads from LDS are 16-lane same-address broadcasts over 4 distinct 16B
// segments -> conflict-free.
// ---------------------------------------------------------------------------
__global__ __launch_bounds__(256, 4) void attn_main(
    const float* __restrict__ x, const u16* __restrict__ Qbh,
    const u16* __restrict__ Kbh, const float* __restrict__ A2,
    const float* __restrict__ B2, const float* __restrict__ c2p,
    float* __restrict__ part_l, float* __restrict__ part_o) {
  // [0..8191]: x-slice [b][512 j]; [8192..8703]: A2 slice.
  // Epilogue reuses [0..1023] (l) and [4096..5119] (o) after a barrier.
  __shared__ __align__(16) float smem[16 * 512 + 512];

  const int t = threadIdx.x;
  const int lane = t & 63, w = t >> 6;
  const int il = lane & 15, h = lane >> 4;
  const int i0 = blockIdx.x * 16;
  const int js = blockIdx.y;
  const int jb = js * JRANGE;

  const float c2 = *c2p;
  const float B2i = B2[i0 + il];

  // --- stage x-slice + A2-slice into LDS (coalesced float4) ---
#pragma unroll
  for (int it = 0; it < 8; ++it) {
    const int flat = it * 256 + t;          // 0..2047 float4s
    const int b = flat >> 7, c4 = flat & 127;
    *(float4*)(&smem[b * 512 + c4 * 4]) =
        *(const float4*)(x + b * NN + jb + c4 * 4);
  }
  if (t < 128)
    *(float4*)(&smem[8192 + t * 4]) = *(const float4*)(A2 + jb + t * 4);

  // Q fragments for this i-tile (B-operand), loaded once.
  short8 qfr[4];
#pragma unroll
  for (int ks = 0; ks < 4; ++ks)
    qfr[ks] = *(const short8*)(Qbh + (i0 + il) * DD + ks * 32 + h * 8);

  // x[b][i] for all 16 batches (this lane's i).
  float xi[16];
#pragma unroll
  for (int b = 0; b < 16; ++b) xi[b] = x[b * NN + i0 + il];

  float l[16], o[16];
#pragma unroll
  for (int b = 0; b < 16; ++b) { l[b] = 0.f; o[b] = 0.f; }

  __syncthreads();

  const float* xw  = &smem[w * WJ + 4 * h];          // + b*512 + c*16
  const float* a2w = &smem[8192 + w * WJ + 4 * h];   // + c*16
  const u16*   kb  = Kbh + (jb + w * WJ + il) * DD + h * 8;

  // prologue: K-frags for chunk 0
  short8 kfr[4];
#pragma unroll
  for (int ks = 0; ks < 4; ++ks) kfr[ks] = *(const short8*)(kb + ks * 32);

  for (int c = 0; c < NCH; ++c) {
    // M' for this chunk: lane holds i = il, j = jb + w*WJ + c*16 + 4h + v
    f32x4 acc = {0.f, 0.f, 0.f, 0.f};
#pragma unroll
    for (int ks = 0; ks < 4; ++ks)
      acc = __builtin_amdgcn_mfma_f32_16x16x32_bf16(kfr[ks], qfr[ks], acc, 0, 0, 0);

    // prefetch next chunk's K-frags (lands during the ~700-cycle b-loop)
    if (c + 1 < NCH) {
      const u16* kbn = kb + (c + 1) * 16 * DD;
#pragma unroll
      for (int ks = 0; ks < 4; ++ks) kfr[ks] = *(const short8*)(kbn + ks * 32);
    }

    const float4 a2c = *(const float4*)(a2w + c * 16);
    const float* xc = xw + c * 16;

#pragma unroll
    for (int b = 0; b < 16; ++b) {
      const float4 xv = *(const float4*)(xc + b * 512);   // LDS broadcast read
      const float Vb = fmaf(c2, xi[b], B2i);
      const float t0 = fmaf(xi[b], a2c.x, acc[0]);
      const float t1 = fmaf(xi[b], a2c.y, acc[1]);
      const float t2 = fmaf(xi[b], a2c.z, acc[2]);
      const float t3 = fmaf(xi[b], a2c.w, acc[3]);
      const float s0 = fmaf(xv.x, Vb, t0);
      const float s1 = fmaf(xv.y, Vb, t1);
      const float s2 = fmaf(xv.z, Vb, t2);
      const float s3 = fmaf(xv.w, Vb, t3);
      const float e0 = __builtin_amdgcn_exp2f(s0);
      const float e1 = __builtin_amdgcn_exp2f(s1);
      const float e2 = __builtin_amdgcn_exp2f(s2);
      const float e3 = __builtin_amdgcn_exp2f(s3);
      l[b] += (e0 + e1) + (e2 + e3);
      float ob = o[b];
      ob = fmaf(e0, xv.x, ob);
      ob = fmaf(e1, xv.y, ob);
      ob = fmaf(e2, xv.z, ob);
      ob = fmaf(e3, xv.w, ob);
      o[b] = ob;
    }
  }

  // --- epilogue: reduce over h, then across waves (reuse smem after barrier)
  __syncthreads();   // all waves done reading x/A2 regions
#pragma unroll
  for (int b = 0; b < 16; ++b) {
    float lv = l[b], ov = o[b];
    lv += __shfl_xor(lv, 16); lv += __shfl_xor(lv, 32);
    ov += __shfl_xor(ov, 16); ov += __shfl_xor(ov, 32);
    if (h == 0) {
      smem[(w * 16 + b) * 16 + il]        = lv;
      smem[4096 + (w * 16 + b) * 16 + il] = ov;
    }
  }
  __syncthreads();

  {
    const int b = t >> 4, ii = t & 15;
    float lsum = 0.f, osum = 0.f;
#pragma unroll
    for (int ww = 0; ww < 4; ++ww) {
      lsum += smem[(ww * 16 + b) * 16 + ii];
      osum += smem[4096 + (ww * 16 + b) * 16 + ii];
    }
    const int outidx = (js * NB + b) * NN + i0 + ii;
    part_l[outidx] = lsum;
    part_o[outidx] = osum;
  }
}

// ---------------------------------------------------------------------------
// Kernel 3: deterministic combine of the JSPLIT partial sums; out = Σo / Σl.
// ---------------------------------------------------------------------------
__global__ void combine_kernel(const float* __restrict__ part_l,
                               const float* __restrict__ part_o,
                               float* __restrict__ out) {
  const int id = blockIdx.x * 256 + threadIdx.x;  // b*NN + i
  float l = 0.f, o = 0.f;
#pragma unroll
  for (int js = 0; js < JSPLIT; ++js) {
    l += part_l[js * (NB * NN) + id];
    o += part_o[js * (NB * NN) + id];
  }
  out[id] = o / l;
}

extern "C" void kernel_launch(void* const* d_in, const int* in_sizes, int n_in,
                              void* d_out, int out_size, void* d_ws, size_t ws_size,
                              hipStream_t stream) {
  const float* x   = (const float*)d_in[0];
  const float* q_w = (const float*)d_in[1];
  const float* q_b = (const float*)d_in[2];
  const float* k_w = (const float*)d_in[3];
  const float* k_b = (const float*)d_in[4];
  const float* pe  = (const float*)d_in[5];
  float* out = (float*)d_out;

  // workspace layout (~6.05 MB, same footprint as the passing round-3 run)
  char* ws = (char*)d_ws;
  u16*   Qbh    = (u16*)(ws);                                    // 1 MB
  u16*   Kbh    = (u16*)(ws + (1u << 20));                       // 1 MB
  float* A2     = (float*)(ws + (2u << 20));                     // 16 KB
  float* B2     = (float*)(ws + (2u << 20) + (16u << 10));       // 16 KB
  float* c2p    = (float*)(ws + (2u << 20) + (32u << 10));       // 64 B
  float* part_l = (float*)(ws + (2u << 20) + (48u << 10));       // 2 MB
  float* part_o = (float*)(ws + (2u << 20) + (48u << 10) + (2u << 20)); // 2 MB

  precomp_kernel<<<NN / 4, 256, 0, stream>>>(q_w, q_b, k_w, k_b, pe,
                                             Qbh, Kbh, A2, B2, c2p);
  attn_main<<<dim3(NN / 16, JSPLIT), 256, 0, stream>>>(x, Qbh, Kbh, A2, B2, c2p,
                                                       part_l, part_o);
  combine_kernel<<<(NB * NN) / 256, 256, 0, stream>>>(part_l, part_o, out);
}